// Round 1
// baseline (812.443 us; speedup 1.0000x reference)
//
#include <hip/hip_runtime.h>
#include <math.h>

// Problem constants (RobertaHedgehogSelfAttention): B=2,S=2048,E=1024,H=16,D=64
constexpr int B = 2, S = 2048, E = 1024, H = 16, D = 64;
constexpr int M = B * S;  // 4096 rows

#define TILE 64
#define BK 16

// C[M,N] = A[M,K] @ W[N,K]^T + bias[N]   (both operands K-contiguous, "NT")
__global__ __launch_bounds__(256) void gemm_nt_bias(const float* __restrict__ A,
                                                    const float* __restrict__ W,
                                                    const float* __restrict__ bias,
                                                    float* __restrict__ C,
                                                    int K, int N) {
  __shared__ float As[BK][TILE + 4];  // +4 pad keeps float4 alignment, breaks bank stride
  __shared__ float Ws[BK][TILE + 4];
  const int tid = threadIdx.x;
  const int tx = tid & 15;   // col group: cols tx*4..tx*4+3
  const int ty = tid >> 4;   // row group: rows ty*4..ty*4+3
  const int bm = blockIdx.x * TILE;
  const int bn = blockIdx.y * TILE;
  const int lk = tid & (BK - 1);  // k index within tile
  const int lr = tid >> 4;        // base row for loads

  float acc[4][4] = {};

  for (int k0 = 0; k0 < K; k0 += BK) {
#pragma unroll
    for (int i = 0; i < 4; ++i) {
      const int r = lr + i * 16;
      As[lk][r] = A[(size_t)(bm + r) * K + k0 + lk];
      Ws[lk][r] = W[(size_t)(bn + r) * K + k0 + lk];
    }
    __syncthreads();
#pragma unroll
    for (int kk = 0; kk < BK; ++kk) {
      float a[4], w[4];
#pragma unroll
      for (int i = 0; i < 4; ++i) a[i] = As[kk][ty * 4 + i];
#pragma unroll
      for (int j = 0; j < 4; ++j) w[j] = Ws[kk][tx * 4 + j];
#pragma unroll
      for (int i = 0; i < 4; ++i)
#pragma unroll
        for (int j = 0; j < 4; ++j) acc[i][j] = fmaf(a[i], w[j], acc[i][j]);
    }
    __syncthreads();
  }

#pragma unroll
  for (int i = 0; i < 4; ++i) {
    const int m = bm + ty * 4 + i;
#pragma unroll
    for (int j = 0; j < 4; ++j) {
      const int n = bn + tx * 4 + j;
      C[(size_t)m * N + n] = acc[i][j] + bias[n];
    }
  }
}

// In-place row softmax over E=1024 columns; one block (256 threads) per row.
__global__ __launch_bounds__(256) void softmax_rows(float* __restrict__ X) {
  const int row = blockIdx.x;
  float* x = X + (size_t)row * E;
  const int tid = threadIdx.x;
  float v[4];
  float mx = -3.4e38f;
#pragma unroll
  for (int i = 0; i < 4; ++i) {
    v[i] = x[tid + i * 256];
    mx = fmaxf(mx, v[i]);
  }
#pragma unroll
  for (int off = 32; off; off >>= 1) mx = fmaxf(mx, __shfl_xor(mx, off, 64));
  __shared__ float redm[4], reds[4];
  if ((tid & 63) == 0) redm[tid >> 6] = mx;
  __syncthreads();
  mx = fmaxf(fmaxf(redm[0], redm[1]), fmaxf(redm[2], redm[3]));
  float s = 0.f;
#pragma unroll
  for (int i = 0; i < 4; ++i) {
    v[i] = expf(v[i] - mx);
    s += v[i];
  }
#pragma unroll
  for (int off = 32; off; off >>= 1) s += __shfl_xor(s, off, 64);
  if ((tid & 63) == 0) reds[tid >> 6] = s;
  __syncthreads();
  s = reds[0] + reds[1] + reds[2] + reds[3];
  const float inv = 1.0f / s;
#pragma unroll
  for (int i = 0; i < 4; ++i) x[tid + i * 256] = v[i] * inv;
}

// KV[bh][d][d'] += sum_t k[t][h*D+d] * v[t][h*D+d'];  ksum[bh][d] += sum_t k[t][h*D+d]
// grid = (B*H, S/128); each block handles 128 timesteps, outer-product microtile 4x4.
__global__ __launch_bounds__(256) void kv_kernel(const float* __restrict__ kf,
                                                 const float* __restrict__ v,
                                                 float* __restrict__ KV,
                                                 float* __restrict__ ksum) {
  const int bh = blockIdx.x;
  const int b = bh / H;
  const int h = bh % H;
  const int t0 = blockIdx.y * 128;
  const float* kbase = kf + (size_t)b * S * E + (size_t)h * D;
  const float* vbase = v + (size_t)b * S * E + (size_t)h * D;

  __shared__ float ks[16][D];
  __shared__ float vs[16][D];

  const int tid = threadIdx.x;
  const int a4 = tid & 15;  // k-dim group: d = a4*4..+3
  const int b4 = tid >> 4;  // v-dim group: d' = b4*4..+3

  float acc[4][4] = {};
  float ksm[4] = {};

  for (int ts = 0; ts < 128; ts += 16) {
#pragma unroll
    for (int i = 0; i < 4; ++i) {
      const int idx = tid + i * 256;
      const int tt = idx >> 6;
      const int d = idx & 63;
      const size_t roff = (size_t)(t0 + ts + tt) * E + d;
      ks[tt][d] = kbase[roff];
      vs[tt][d] = vbase[roff];
    }
    __syncthreads();
#pragma unroll
    for (int tt = 0; tt < 16; ++tt) {
      float kk4[4], vv4[4];
#pragma unroll
      for (int i = 0; i < 4; ++i) kk4[i] = ks[tt][a4 * 4 + i];
#pragma unroll
      for (int j = 0; j < 4; ++j) vv4[j] = vs[tt][b4 * 4 + j];
#pragma unroll
      for (int i = 0; i < 4; ++i) {
        ksm[i] += kk4[i];
#pragma unroll
        for (int j = 0; j < 4; ++j) acc[i][j] = fmaf(kk4[i], vv4[j], acc[i][j]);
      }
    }
    __syncthreads();
  }
#pragma unroll
  for (int i = 0; i < 4; ++i)
#pragma unroll
    for (int j = 0; j < 4; ++j)
      atomicAdd(&KV[((size_t)bh * D + a4 * 4 + i) * D + b4 * 4 + j], acc[i][j]);
  if (b4 == 0) {
#pragma unroll
    for (int i = 0; i < 4; ++i) atomicAdd(&ksum[bh * D + a4 * 4 + i], ksm[i]);
  }
}

// out[row][h*D+d'] = (sum_d q[row][h*D+d]*KV[bh][d][d']) / (sum_d q[row][h*D+d]*ksum[bh][d])
// one block per row (b,s); thread (h = tid/16, g = tid%16) computes d' = g*4..+3.
__global__ __launch_bounds__(256) void out_kernel(const float* __restrict__ qf,
                                                  const float* __restrict__ KV,
                                                  const float* __restrict__ ksum,
                                                  float* __restrict__ out) {
  const int row = blockIdx.x;
  const int b = row / S;
  const int tid = threadIdx.x;
  __shared__ float q[E];
#pragma unroll
  for (int i = 0; i < 4; ++i) q[tid + i * 256] = qf[(size_t)row * E + tid + i * 256];
  __syncthreads();
  const int h = tid >> 4;
  const int g = tid & 15;
  const int bh = b * H + h;
  const float* ksb = ksum + bh * D;
  float dpart = 0.f;
#pragma unroll
  for (int j = 0; j < 4; ++j) dpart += q[h * D + g * 4 + j] * ksb[g * 4 + j];
#pragma unroll
  for (int off = 8; off; off >>= 1) dpart += __shfl_xor(dpart, off, 16);
  const float inv = 1.0f / dpart;
  const float* KVb = KV + (size_t)bh * D * D + g * 4;
  float num[4] = {};
#pragma unroll 8
  for (int d = 0; d < D; ++d) {
    const float qd = q[h * D + d];
#pragma unroll
    for (int j = 0; j < 4; ++j) num[j] = fmaf(qd, KVb[(size_t)d * D + j], num[j]);
  }
#pragma unroll
  for (int j = 0; j < 4; ++j) out[(size_t)row * E + h * D + g * 4 + j] = num[j] * inv;
}

extern "C" void kernel_launch(void* const* d_in, const int* in_sizes, int n_in,
                              void* d_out, int out_size, void* d_ws, size_t ws_size,
                              hipStream_t stream) {
  const float* hs = (const float*)d_in[0];
  const float* Wq = (const float*)d_in[1];
  const float* bq = (const float*)d_in[2];
  const float* Wk = (const float*)d_in[3];
  const float* bk = (const float*)d_in[4];
  const float* Wv = (const float*)d_in[5];
  const float* bv = (const float*)d_in[6];
  const float* Wfq = (const float*)d_in[7];
  const float* bfq = (const float*)d_in[8];
  const float* Wfk = (const float*)d_in[9];
  const float* bfk = (const float*)d_in[10];
  float* out = (float*)d_out;

  // Workspace layout (3 big buffers reused + tiny KV/ksum): 48.5 MB total.
  float* buf0 = (float*)d_ws;                 // q_lin -> k_lin -> v
  float* buf1 = buf0 + (size_t)M * E;         // qf (logits, softmaxed in place)
  float* buf2 = buf1 + (size_t)M * E;         // kf
  float* KV = buf2 + (size_t)M * E;           // [B*H, D, D]
  float* ksum = KV + (size_t)B * H * D * D;   // [B*H, D]

  const dim3 gg(M / TILE, E / TILE);

  gemm_nt_bias<<<gg, 256, 0, stream>>>(hs, Wq, bq, buf0, E, E);      // q_lin
  gemm_nt_bias<<<gg, 256, 0, stream>>>(buf0, Wfq, bfq, buf1, E, E);  // q feature logits
  softmax_rows<<<M, 256, 0, stream>>>(buf1);                         // qf
  gemm_nt_bias<<<gg, 256, 0, stream>>>(hs, Wk, bk, buf0, E, E);      // k_lin
  gemm_nt_bias<<<gg, 256, 0, stream>>>(buf0, Wfk, bfk, buf2, E, E);  // k feature logits
  softmax_rows<<<M, 256, 0, stream>>>(buf2);                         // kf
  gemm_nt_bias<<<gg, 256, 0, stream>>>(hs, Wv, bv, buf0, E, E);      // v

  hipMemsetAsync(KV, 0, ((size_t)B * H * D * D + (size_t)B * H * D) * sizeof(float), stream);
  kv_kernel<<<dim3(B * H, S / 128), 256, 0, stream>>>(buf2, buf0, KV, ksum);
  out_kernel<<<M, 256, 0, stream>>>(buf1, KV, ksum, out);
}

// Round 2
// 306.940 us; speedup vs baseline: 2.6469x; 2.6469x over previous
//
#include <hip/hip_runtime.h>
#include <math.h>

constexpr int B = 2, S = 2048, E = 1024, H = 16, D = 64;
constexpr int M = B * S;  // 4096

typedef __attribute__((ext_vector_type(8))) short short8;
typedef __attribute__((ext_vector_type(4))) float f32x4;
#define MFMA_BF16 __builtin_amdgcn_mfma_f32_16x16x32_bf16

// Split fp32 x into hi = bf16-truncate(x), lo = bf16-truncate(x - hi). Combined rel err ~2^-16.
__device__ __forceinline__ void cvt_split4(float4 v, short* __restrict__ hi, short* __restrict__ lo) {
  float f[4] = {v.x, v.y, v.z, v.w};
  short hh[4], ll[4];
#pragma unroll
  for (int i = 0; i < 4; ++i) {
    unsigned u = __float_as_uint(f[i]);
    hh[i] = (short)(u >> 16);
    float rem = f[i] - __uint_as_float(u & 0xFFFF0000u);
    ll[i] = (short)(__float_as_uint(rem) >> 16);
  }
  *(short4*)hi = make_short4(hh[0], hh[1], hh[2], hh[3]);
  *(short4*)lo = make_short4(ll[0], ll[1], ll[2], ll[3]);
}

// C[m,n] = sum_k A[m,k]*W[n,k] + bias[n], fp32 in/out, split-bf16 3-MFMA accumulation.
// BM=128 fixed; BN = 128 (waves 2x2 of 64x64) or 64 (waves 4x1 of 32x64). 256 threads.
// blockIdx.z selects operand set (z-batched independent GEMMs).
template <int BN>
__global__ __launch_bounds__(256, 2) void gemm_split_nt(
    const float* __restrict__ A0, const float* __restrict__ W0,
    const float* __restrict__ b0, float* __restrict__ C0,
    const float* __restrict__ A1, const float* __restrict__ W1,
    const float* __restrict__ b1, float* __restrict__ C1, int K, int N) {
  const float* A = blockIdx.z ? A1 : A0;
  const float* W = blockIdx.z ? W1 : W0;
  const float* bias = blockIdx.z ? b1 : b0;
  float* C = blockIdx.z ? C1 : C0;

  constexpr int LDR = 40;            // padded LDS row (32 bf16 + 8 pad) breaks b128 conflicts
  constexpr int BPB = BN / 32;       // B staging passes
  __shared__ short Ahi[128 * LDR], Alo[128 * LDR];
  __shared__ short Bhi[BN * LDR], Blo[BN * LDR];

  const int tid = threadIdx.x;
  const int bm = blockIdx.x * 128, bn = blockIdx.y * BN;
  const int lr = tid >> 3, lc = (tid & 7) * 4;  // staging: row, k-offset

  const int wave = tid >> 6, lane = tid & 63;
  constexpr int MT = (BN == 128) ? 4 : 2;  // m-tiles per wave
  const int wm = (BN == 128) ? (wave & 1) * 64 : wave * 32;
  const int wn = (BN == 128) ? (wave >> 1) * 64 : 0;
  const int fr = lane & 15;        // row (A) / col (B) within 16-tile
  const int fk = (lane >> 4) * 8;  // k offset within 32-slab

  f32x4 acc[MT][4] = {};
  float4 pa[4], pb[BPB];

#pragma unroll
  for (int p = 0; p < 4; ++p)
    pa[p] = *(const float4*)(A + (size_t)(bm + lr + p * 32) * K + lc);
#pragma unroll
  for (int p = 0; p < BPB; ++p)
    pb[p] = *(const float4*)(W + (size_t)(bn + lr + p * 32) * K + lc);

  for (int k0 = 0; k0 < K; k0 += 32) {
#pragma unroll
    for (int p = 0; p < 4; ++p) {
      const int base = (lr + p * 32) * LDR + lc;
      cvt_split4(pa[p], &Ahi[base], &Alo[base]);
    }
#pragma unroll
    for (int p = 0; p < BPB; ++p) {
      const int base = (lr + p * 32) * LDR + lc;
      cvt_split4(pb[p], &Bhi[base], &Blo[base]);
    }
    __syncthreads();
    if (k0 + 32 < K) {
#pragma unroll
      for (int p = 0; p < 4; ++p)
        pa[p] = *(const float4*)(A + (size_t)(bm + lr + p * 32) * K + k0 + 32 + lc);
#pragma unroll
      for (int p = 0; p < BPB; ++p)
        pb[p] = *(const float4*)(W + (size_t)(bn + lr + p * 32) * K + k0 + 32 + lc);
    }
    short8 ah[MT], al[MT], bh[4], bl[4];
#pragma unroll
    for (int i = 0; i < MT; ++i) {
      const int ab = (wm + i * 16 + fr) * LDR + fk;
      ah[i] = *(const short8*)&Ahi[ab];
      al[i] = *(const short8*)&Alo[ab];
    }
#pragma unroll
    for (int i = 0; i < 4; ++i) {
      const int bb = (wn + i * 16 + fr) * LDR + fk;
      bh[i] = *(const short8*)&Bhi[bb];
      bl[i] = *(const short8*)&Blo[bb];
    }
#pragma unroll
    for (int mi = 0; mi < MT; ++mi)
#pragma unroll
      for (int ni = 0; ni < 4; ++ni) {
        acc[mi][ni] = MFMA_BF16(ah[mi], bh[ni], acc[mi][ni], 0, 0, 0);
        acc[mi][ni] = MFMA_BF16(ah[mi], bl[ni], acc[mi][ni], 0, 0, 0);
        acc[mi][ni] = MFMA_BF16(al[mi], bh[ni], acc[mi][ni], 0, 0, 0);
      }
    __syncthreads();
  }

#pragma unroll
  for (int ni = 0; ni < 4; ++ni) {
    const int n = bn + wn + ni * 16 + fr;
    const float bv = bias ? bias[n] : 0.0f;
#pragma unroll
    for (int mi = 0; mi < MT; ++mi) {
      const int m0 = bm + wm + mi * 16 + (lane >> 4) * 4;
#pragma unroll
      for (int r = 0; r < 4; ++r)
        C[(size_t)(m0 + r) * N + n] = acc[mi][ni][r] + bv;
    }
  }
}

// out[k][j] = in[j][k] for two 1024x1024 matrices (z selects).
__global__ __launch_bounds__(256) void transpose2(const float* __restrict__ i0, float* __restrict__ o0,
                                                  const float* __restrict__ i1, float* __restrict__ o1) {
  const float* in = blockIdx.z ? i1 : i0;
  float* out = blockIdx.z ? o1 : o0;
  __shared__ float t[32][33];
  const int x = threadIdx.x & 31, y0 = threadIdx.x >> 5;
  const int bx = blockIdx.x * 32, by = blockIdx.y * 32;
#pragma unroll
  for (int i = 0; i < 32; i += 8) t[y0 + i][x] = in[(size_t)(by + y0 + i) * E + bx + x];
  __syncthreads();
#pragma unroll
  for (int i = 0; i < 32; i += 8) out[(size_t)(bx + y0 + i) * E + by + x] = t[x][y0 + i];
}

// o[n] = dot(Wf[n,:], bin) + bf[n]; one wave per n; blockIdx.y selects set.
__global__ __launch_bounds__(256) void bias_combine2(
    const float* __restrict__ Wf0, const float* __restrict__ b0, const float* __restrict__ bf0, float* __restrict__ o0,
    const float* __restrict__ Wf1, const float* __restrict__ b1, const float* __restrict__ bf1, float* __restrict__ o1) {
  const float* Wf = blockIdx.y ? Wf1 : Wf0;
  const float* bin = blockIdx.y ? b1 : b0;
  const float* bf = blockIdx.y ? bf1 : bf0;
  float* o = blockIdx.y ? o1 : o0;
  const int lane = threadIdx.x & 63;
  const int n = blockIdx.x * 4 + (threadIdx.x >> 6);
  float s = 0.f;
  for (int j = lane; j < E; j += 64) s += Wf[(size_t)n * E + j] * bin[j];
#pragma unroll
  for (int off = 32; off; off >>= 1) s += __shfl_xor(s, off, 64);
  if (lane == 0) o[n] = s + bf[n];
}

// In-place row softmax over E columns; blockIdx.y selects buffer.
__global__ __launch_bounds__(256) void softmax2(float* __restrict__ X0, float* __restrict__ X1) {
  float* X = blockIdx.y ? X1 : X0;
  float* x = X + (size_t)blockIdx.x * E;
  const int tid = threadIdx.x;
  float v[4];
  float mx = -3.4e38f;
#pragma unroll
  for (int i = 0; i < 4; ++i) {
    v[i] = x[tid + i * 256];
    mx = fmaxf(mx, v[i]);
  }
#pragma unroll
  for (int off = 32; off; off >>= 1) mx = fmaxf(mx, __shfl_xor(mx, off, 64));
  __shared__ float redm[4], reds[4];
  if ((tid & 63) == 0) redm[tid >> 6] = mx;
  __syncthreads();
  mx = fmaxf(fmaxf(redm[0], redm[1]), fmaxf(redm[2], redm[3]));
  float s = 0.f;
#pragma unroll
  for (int i = 0; i < 4; ++i) {
    v[i] = expf(v[i] - mx);
    s += v[i];
  }
#pragma unroll
  for (int off = 32; off; off >>= 1) s += __shfl_xor(s, off, 64);
  if ((tid & 63) == 0) reds[tid >> 6] = s;
  __syncthreads();
  s = reds[0] + reds[1] + reds[2] + reds[3];
  const float inv = 1.0f / s;
#pragma unroll
  for (int i = 0; i < 4; ++i) x[tid + i * 256] = v[i] * inv;
}

// KV[bh][d][d'] += sum_t k[t]*v[t]; ksum[bh][d] += sum_t k[t]
__global__ __launch_bounds__(256) void kv_kernel(const float* __restrict__ kf,
                                                 const float* __restrict__ v,
                                                 float* __restrict__ KV,
                                                 float* __restrict__ ksum) {
  const int bh = blockIdx.x;
  const int b = bh / H, h = bh % H;
  const int t0 = blockIdx.y * 128;
  const float* kbase = kf + (size_t)b * S * E + (size_t)h * D;
  const float* vbase = v + (size_t)b * S * E + (size_t)h * D;
  __shared__ float ks[16][D];
  __shared__ float vs[16][D];
  const int tid = threadIdx.x;
  const int a4 = tid & 15, b4 = tid >> 4;
  float acc[4][4] = {};
  float ksm[4] = {};
  for (int ts = 0; ts < 128; ts += 16) {
#pragma unroll
    for (int i = 0; i < 4; ++i) {
      const int idx = tid + i * 256;
      const int tt = idx >> 6, d = idx & 63;
      const size_t roff = (size_t)(t0 + ts + tt) * E + d;
      ks[tt][d] = kbase[roff];
      vs[tt][d] = vbase[roff];
    }
    __syncthreads();
#pragma unroll
    for (int tt = 0; tt < 16; ++tt) {
      float kk4[4], vv4[4];
#pragma unroll
      for (int i = 0; i < 4; ++i) kk4[i] = ks[tt][a4 * 4 + i];
#pragma unroll
      for (int j = 0; j < 4; ++j) vv4[j] = vs[tt][b4 * 4 + j];
#pragma unroll
      for (int i = 0; i < 4; ++i) {
        ksm[i] += kk4[i];
#pragma unroll
        for (int j = 0; j < 4; ++j) acc[i][j] = fmaf(kk4[i], vv4[j], acc[i][j]);
      }
    }
    __syncthreads();
  }
#pragma unroll
  for (int i = 0; i < 4; ++i)
#pragma unroll
    for (int j = 0; j < 4; ++j)
      atomicAdd(&KV[((size_t)bh * D + a4 * 4 + i) * D + b4 * 4 + j], acc[i][j]);
  if (b4 == 0) {
#pragma unroll
    for (int i = 0; i < 4; ++i) atomicAdd(&ksum[bh * D + a4 * 4 + i], ksm[i]);
  }
}

__global__ __launch_bounds__(256) void out_kernel(const float* __restrict__ qf,
                                                  const float* __restrict__ KV,
                                                  const float* __restrict__ ksum,
                                                  float* __restrict__ out) {
  const int row = blockIdx.x;
  const int b = row / S;
  const int tid = threadIdx.x;
  __shared__ float q[E];
#pragma unroll
  for (int i = 0; i < 4; ++i) q[tid + i * 256] = qf[(size_t)row * E + tid + i * 256];
  __syncthreads();
  const int h = tid >> 4, g = tid & 15;
  const int bh = b * H + h;
  const float* ksb = ksum + bh * D;
  float dpart = 0.f;
#pragma unroll
  for (int j = 0; j < 4; ++j) dpart += q[h * D + g * 4 + j] * ksb[g * 4 + j];
#pragma unroll
  for (int off = 8; off; off >>= 1) dpart += __shfl_xor(dpart, off, 16);
  const float inv = 1.0f / dpart;
  const float* KVb = KV + (size_t)bh * D * D + g * 4;
  float num[4] = {};
#pragma unroll 8
  for (int d = 0; d < D; ++d) {
    const float qd = q[h * D + d];
#pragma unroll
    for (int j = 0; j < 4; ++j) num[j] = fmaf(qd, KVb[(size_t)d * D + j], num[j]);
  }
#pragma unroll
  for (int j = 0; j < 4; ++j) out[(size_t)row * E + h * D + g * 4 + j] = num[j] * inv;
}

extern "C" void kernel_launch(void* const* d_in, const int* in_sizes, int n_in,
                              void* d_out, int out_size, void* d_ws, size_t ws_size,
                              hipStream_t stream) {
  const float* hs = (const float*)d_in[0];
  const float* Wq = (const float*)d_in[1];
  const float* bq = (const float*)d_in[2];
  const float* Wk = (const float*)d_in[3];
  const float* bk = (const float*)d_in[4];
  const float* Wv = (const float*)d_in[5];
  const float* bv = (const float*)d_in[6];
  const float* Wfq = (const float*)d_in[7];
  const float* bfq = (const float*)d_in[8];
  const float* Wfk = (const float*)d_in[9];
  const float* bfk = (const float*)d_in[10];
  float* out = (float*)d_out;

  const size_t MEG = 1024 * 1024;
  float* qf = (float*)d_ws;            // [M,E] logits_q -> qf (16 MB)
  float* kf = qf + 4 * MEG;            // [M,E] (16 MB)
  float* vreg = kf + 4 * MEG;          // [M,E] v (16 MB); early scratch lives inside:
  float* WqT = vreg;                   //   1 MB floats (dead before v written)
  float* WkT = vreg + 1 * MEG;
  float* WcQ = vreg + 2 * MEG;
  float* WcK = vreg + 3 * MEG;
  float* bcQ = vreg + 4 * MEG;         // after vreg: 1024
  float* bcK = bcQ + 1024;
  float* KV = bcK + 1024;              // [B*H, D, D] = 131072 floats
  float* ksum = KV + (size_t)B * H * D * D;  // 2048 floats

  // 1) Transpose Wq, Wk (for the NT-form weight-combine GEMM).
  transpose2<<<dim3(32, 32, 2), 256, 0, stream>>>(Wq, WqT, Wk, WkT);
  // 2) Combined biases: bc = Wf @ b + bf.
  bias_combine2<<<dim3(256, 2), 256, 0, stream>>>(Wfq, bq, bfq, bcQ, Wfk, bk, bfk, bcK);
  // 3) Combined weights: Wc = Wf @ W  (NT gemm vs W^T).  [1024,1024,K=1024] x2
  gemm_split_nt<64><<<dim3(8, 16, 2), 256, 0, stream>>>(Wfq, WqT, nullptr, WcQ,
                                                        Wfk, WkT, nullptr, WcK, E, E);
  // 4) Feature logits: hs @ Wc^T + bc  (q and k z-batched, 512 blocks).
  gemm_split_nt<128><<<dim3(32, 8, 2), 256, 0, stream>>>(hs, WcQ, bcQ, qf,
                                                         hs, WcK, bcK, kf, E, E);
  // 5) Row softmax (both buffers).
  softmax2<<<dim3(M, 2), 256, 0, stream>>>(qf, kf);
  // 6) v = hs @ Wv^T + bv  (BN=64 -> 512 blocks). Overwrites the early scratch.
  gemm_split_nt<64><<<dim3(32, 16, 1), 256, 0, stream>>>(hs, Wv, bv, vreg,
                                                         hs, Wv, bv, vreg, E, E);
  // 7) KV accumulation + output.
  hipMemsetAsync(KV, 0, ((size_t)B * H * D * D + (size_t)B * H * D) * sizeof(float), stream);
  kv_kernel<<<dim3(B * H, S / 128), 256, 0, stream>>>(kf, vreg, KV, ksum);
  out_kernel<<<M, 256, 0, stream>>>(qf, KV, ksum, out);
}